// Round 1
// baseline (1364.366 us; speedup 1.0000x reference)
//
#include <hip/hip_runtime.h>
#include <math.h>

#define BATCH 128
#define T 250
#define D_IN 700
#define H 256
#define D_OUT 20

typedef float v2f __attribute__((ext_vector_type(2)));
typedef __attribute__((ext_vector_type(8))) short bf16x8;
typedef __attribute__((ext_vector_type(4))) float f32x4;

static __device__ __forceinline__ unsigned short f2b(float f) {
    unsigned u = __float_as_uint(f);
    u += 0x7FFFu + ((u >> 16) & 1u);
    return (unsigned short)(u >> 16);
}

// ---------------------------------------------------------------------------
// Workspace layout:
//   U     [32001][256] f32   (pad row: u-prefetch overrun at t=249)
//   C1    [257][512] f32     row k: q=2h -> W12T[k][h], q=2h+1 -> W11T[k][h]
//   C2    [257][512] f32     row k: q=2h -> W22T[k][h], q=2h+1 -> (h<20 ? Wo[h][k] : 0)
//   Wi1p  [256][704] bf16    cols 700..703 zero (MFMA K-pad)
//   row 256 of C1/C2 is all-zero (spike-list padding target)
// Column-split recurrent: thread tid owns columns {2*tid, 2*tid+1} of every
// row -> one v2f load per spike row, gather result lands on the thread that
// owns neuron tid. No cross-wave reduction needed.
// ---------------------------------------------------------------------------
#define N_C  (257 * 512)
#define N_WP (256 * 704)

__global__ void prep_k(const float* __restrict__ Wi1, const float* __restrict__ W11,
                       const float* __restrict__ W12, const float* __restrict__ W22,
                       const float* __restrict__ Wo,
                       unsigned short* __restrict__ Wi1p, float* __restrict__ C1,
                       float* __restrict__ C2) {
    int idx = blockIdx.x * 256 + threadIdx.x;
    if (idx < N_C) {
        int k = idx >> 9, q = idx & 511, h = q >> 1;
        float v = 0.f;
        if (k < H) v = (q & 1) ? W11[h * H + k] : W12[h * H + k];
        C1[idx] = v;
        return;
    }
    idx -= N_C;
    if (idx < N_C) {
        int k = idx >> 9, q = idx & 511, h = q >> 1;
        float v = 0.f;
        if (k < H) {
            if (q & 1) v = (h < D_OUT) ? Wo[h * H + k] : 0.f;
            else v = W22[h * H + k];
        }
        C2[idx] = v;
        return;
    }
    idx -= N_C;
    if (idx < N_WP) {
        int h = idx / 704, k = idx - h * 704;
        Wi1p[idx] = (k < D_IN) ? f2b(Wi1[h * D_IN + k]) : (unsigned short)0;
    }
}

// ---------------------------------------------------------------------------
// U = x @ Wi1^T + bi1 via MFMA 16x16x32 bf16 — UNCHANGED (proven).
// ---------------------------------------------------------------------------
__global__ __launch_bounds__(256) void gemm_u_k(const float* __restrict__ x,
                                                const unsigned short* __restrict__ Wi1p,
                                                const float* __restrict__ bi1,
                                                float* __restrict__ U) {
    const int lane = threadIdx.x & 63;
    const int wv = threadIdx.x >> 6;
    const int quad = lane >> 4;
    const int nl = lane & 15;
    const int mbase = blockIdx.x * 64 + wv * 16;
    const int m = mbase + nl;

    f32x4 acc[16];
#pragma unroll
    for (int i = 0; i < 16; ++i) acc[i] = (f32x4)(0.f);

    float bias[16];
#pragma unroll
    for (int nt = 0; nt < 16; ++nt) bias[nt] = bi1[nt * 16 + nl];

    const float* xrow = x + (size_t)m * D_IN;
    const unsigned short* brow = Wi1p + nl * 704 + quad * 8;

    for (int k0 = 0; k0 < 704; k0 += 32) {
        int ka = k0 + quad * 8;
        int ka2 = (ka + 4 <= 696) ? ka + 4 : 696;
        float4 q0 = *(const float4*)(xrow + ka);
        float4 q1 = *(const float4*)(xrow + ka2);
        bf16x8 af;
        af[0] = (short)f2b(q0.x); af[1] = (short)f2b(q0.y);
        af[2] = (short)f2b(q0.z); af[3] = (short)f2b(q0.w);
        af[4] = (short)f2b(q1.x); af[5] = (short)f2b(q1.y);
        af[6] = (short)f2b(q1.z); af[7] = (short)f2b(q1.w);

        const unsigned short* bp = brow + k0;
        bf16x8 bf[16];
#pragma unroll
        for (int nt = 0; nt < 16; ++nt)
            bf[nt] = *(const bf16x8*)(bp + nt * 16 * 704);
#pragma unroll
        for (int nt = 0; nt < 16; ++nt)
            acc[nt] = __builtin_amdgcn_mfma_f32_16x16x32_bf16(af, bf[nt], acc[nt], 0, 0, 0);
    }

#pragma unroll
    for (int nt = 0; nt < 16; ++nt) {
#pragma unroll
        for (int r = 0; r < 4; ++r) {
            U[(size_t)(mbase + quad * 4 + r) * H + nt * 16 + nl] = acc[nt][r] + bias[nt];
        }
    }
}

// ---------------------------------------------------------------------------
// Column-split gather: wave-uniform spike list in LDS, each thread loads its
// own v2f column pair per row. Depth-4 pipeline, 16-row chunks (128 VGPR of
// buffers; fine at 1 wave/SIMD). Pad entries point at the all-zero row 256.
// ---------------------------------------------------------------------------
static __device__ __forceinline__ void ldchunk(const unsigned* __restrict__ lst, int c,
                                               const float* __restrict__ Cb, unsigned toff,
                                               v2f* buf) {
    uint4 a = *(const uint4*)(lst + c);
    uint4 b = *(const uint4*)(lst + c + 4);
    uint4 d = *(const uint4*)(lst + c + 8);
    uint4 e = *(const uint4*)(lst + c + 12);
    unsigned I[16] = {a.x, a.y, a.z, a.w, b.x, b.y, b.z, b.w,
                      d.x, d.y, d.z, d.w, e.x, e.y, e.z, e.w};
#pragma unroll
    for (int j = 0; j < 16; ++j)
        buf[j] = *(const v2f*)(Cb + (I[j] << 9) + toff);
}

static __device__ __forceinline__ void acchunk(const v2f* buf, v2f& A0, v2f& A1) {
#pragma unroll
    for (int j = 0; j < 16; j += 2) { A0 += buf[j]; A1 += buf[j + 1]; }
}

static __device__ __forceinline__ v2f gather_cols(const unsigned* __restrict__ lst, int n,
                                                  const float* __restrict__ Cb, unsigned toff) {
    v2f A0 = (v2f)(0.f), A1 = (v2f)(0.f);
    v2f b0[16], b1[16], b2[16], b3[16];
    int nr = (n + 15) & ~15;
    if (nr < 64) nr = 64;              // prologue always covers 64 entries (pads are zero rows)
    ldchunk(lst, 0,  Cb, toff, b0);
    ldchunk(lst, 16, Cb, toff, b1);
    ldchunk(lst, 32, Cb, toff, b2);
    ldchunk(lst, 48, Cb, toff, b3);
    int c = 64;
    for (; c + 64 <= nr; c += 64) {
        acchunk(b0, A0, A1); ldchunk(lst, c,      Cb, toff, b0);
        acchunk(b1, A0, A1); ldchunk(lst, c + 16, Cb, toff, b1);
        acchunk(b2, A0, A1); ldchunk(lst, c + 32, Cb, toff, b2);
        acchunk(b3, A0, A1); ldchunk(lst, c + 48, Cb, toff, b3);
    }
    int rem = nr - c;                   // 0, 16, 32 or 48 (uniform)
    if (rem > 0)  { acchunk(b0, A0, A1); ldchunk(lst, c,      Cb, toff, b0); }
    if (rem > 16) { acchunk(b1, A0, A1); ldchunk(lst, c + 16, Cb, toff, b1); }
    if (rem > 32) { acchunk(b2, A0, A1); ldchunk(lst, c + 32, Cb, toff, b2); }
    acchunk(b0, A0, A1);
    acchunk(b1, A0, A1);
    acchunk(b2, A0, A1);
    acchunk(b3, A0, A1);
    return A0 + A1;
}

// ---------------------------------------------------------------------------
// Recurrent: one BLOCK (4 waves, 256 threads) per batch element.
// Thread tid owns neuron tid of both layers. Spike lists shared via LDS
// (2 barriers per list build, 4 per step); gathers are barrier-free.
// ---------------------------------------------------------------------------
__global__ __launch_bounds__(256, 1) void recurrent_k(
    const float* __restrict__ U,
    const float* __restrict__ mem1_0, const float* __restrict__ mem2_0,
    const float* __restrict__ memo_0,
    const float* __restrict__ b11v, const float* __restrict__ b12v,
    const float* __restrict__ b22v, const float* __restrict__ bov,
    const float* __restrict__ tau_adp_h1, const float* __restrict__ tau_adp_h2,
    const float* __restrict__ tau_m_h1, const float* __restrict__ tau_m_h2,
    const float* __restrict__ tau_m_o,
    const float* __restrict__ C1, const float* __restrict__ C2,
    float* __restrict__ out)
{
    const int tid = threadIdx.x;
    const int lane = tid & 63;
    const int w = tid >> 6;
    const int bi = blockIdx.x;
    const unsigned toff = 2u * (unsigned)tid;

    __shared__ __align__(16) unsigned list1[320];
    __shared__ __align__(16) unsigned list2[320];
    __shared__ unsigned cnt1[4], cnt2[4];

    float mem1 = mem1_0[bi * H + tid];
    float mem2 = mem2_0[bi * H + tid];
    float b1 = 0.01f, b2s = 0.01f;
    float spk1 = 0.f, spk2 = 0.f;

    float al1 = expf(-1.f / tau_m_h1[tid]);
    float ro1 = expf(-1.f / tau_adp_h1[tid]);
    float al2 = expf(-1.f / tau_m_h2[tid]);
    float ro2 = expf(-1.f / tau_adp_h2[tid]);
    float oma1 = 1.f - al1, omr1 = 1.f - ro1;
    float oma2 = 1.f - al2, omr2 = 1.f - ro2;

    float b11r = b11v[tid];
    float bs2 = b12v[tid] + b22v[tid];

    float memo = 0.f, alpha_o = 0.f, bo_r = 0.f, accv = 0.f;
    if (tid < D_OUT) {
        memo = memo_0[bi * D_OUT + tid];
        alpha_o = expf(-1.f / tau_m_o[tid]);
        bo_r = bov[tid];
    }

    float g11c = 0.f, g22c = 0.f, aOc = 0.f;
    const float* Up = U + (size_t)bi * T * H + tid;
    float u_cur = *Up;
    const unsigned long long below = (1ull << lane) - 1ull;

    for (int t = 0; t < T; ++t) {
        float u_nxt = Up[H];
        Up += H;

        if (t >= 1) {
            float o = bo_r + aOc;
            memo = memo * alpha_o + (1.f - alpha_o) * o;
            if (t >= 12 && w == 0) {
                float e = (lane < D_OUT) ? __expf(memo) : 0.f;
                float s = e;
#pragma unroll
                for (int d = 16; d >= 1; d >>= 1) s += __shfl_xor(s, d, 32);
                if (lane < D_OUT) accv += __fdividef(e, s);
            }
        }

        // ---- layer 1 neuron update (thread-local) ----
        float h1 = u_cur + b11r + g11c;
        b1 = ro1 * b1 + omr1 * spk1;
        float B1 = 0.01f + 1.8f * b1;
        mem1 = mem1 * al1 + oma1 * h1 - B1 * spk1;
        spk1 = (mem1 - B1 > 0.f) ? 1.f : 0.f;

        // ---- build shared spike list 1 ----
        unsigned long long m1 = __ballot(spk1 != 0.f);
        if (lane == 0) cnt1[w] = (unsigned)__popcll(m1);
        __syncthreads();
        unsigned c10 = cnt1[0], c11 = cnt1[1], c12 = cnt1[2], c13 = cnt1[3];
        unsigned n1 = c10 + c11 + c12 + c13;
        unsigned base1 = (w > 0 ? c10 : 0u) + (w > 1 ? c11 : 0u) + (w > 2 ? c12 : 0u);
        if (spk1 != 0.f) list1[base1 + (unsigned)__popcll(m1 & below)] = (unsigned)tid;
        if (tid < 64) list1[n1 + tid] = 256u;   // pad -> all-zero row
        __syncthreads();

        v2f G1 = gather_cols(list1, (int)n1, C1, toff);   // {g12[tid], g11[tid]}

        // ---- layer 2 neuron update ----
        float h2 = bs2 + g22c + G1.x;
        b2s = ro2 * b2s + omr2 * spk2;
        float B2 = 0.01f + 1.8f * b2s;
        mem2 = mem2 * al2 + oma2 * h2 - B2 * spk2;
        spk2 = (mem2 - B2 > 0.f) ? 1.f : 0.f;

        // ---- build shared spike list 2 ----
        unsigned long long m2 = __ballot(spk2 != 0.f);
        if (lane == 0) cnt2[w] = (unsigned)__popcll(m2);
        __syncthreads();
        unsigned c20 = cnt2[0], c21 = cnt2[1], c22 = cnt2[2], c23 = cnt2[3];
        unsigned n2 = c20 + c21 + c22 + c23;
        unsigned base2 = (w > 0 ? c20 : 0u) + (w > 1 ? c21 : 0u) + (w > 2 ? c22 : 0u);
        if (spk2 != 0.f) list2[base2 + (unsigned)__popcll(m2 & below)] = (unsigned)tid;
        if (tid < 64) list2[n2 + tid] = 256u;
        __syncthreads();

        v2f G2 = gather_cols(list2, (int)n2, C2, toff);   // {g22[tid], aO[tid]}

        g11c = G1.y;
        g22c = G2.x;
        aOc = G2.y;
        u_cur = u_nxt;
    }

    // final flush (memo(T-1) + softmax)
    {
        float o = bo_r + aOc;
        memo = memo * alpha_o + (1.f - alpha_o) * o;
        if (w == 0) {
            float e = (lane < D_OUT) ? __expf(memo) : 0.f;
            float s = e;
#pragma unroll
            for (int d = 16; d >= 1; d >>= 1) s += __shfl_xor(s, d, 32);
            if (lane < D_OUT) accv += __fdividef(e, s);
        }
    }
    if (tid < D_OUT) out[bi * D_OUT + tid] = accv;
}

// ---------------------------------------------------------------------------
extern "C" void kernel_launch(void* const* d_in, const int* in_sizes, int n_in,
                              void* d_out, int out_size, void* d_ws, size_t ws_size,
                              hipStream_t stream) {
    const float* x          = (const float*)d_in[0];
    const float* mem1_0     = (const float*)d_in[1];
    const float* mem2_0     = (const float*)d_in[2];
    const float* memo_0     = (const float*)d_in[3];
    const float* Wi1        = (const float*)d_in[4];
    const float* bi1        = (const float*)d_in[5];
    const float* W11        = (const float*)d_in[6];
    const float* b11        = (const float*)d_in[7];
    const float* W12        = (const float*)d_in[8];
    const float* b12        = (const float*)d_in[9];
    const float* W22        = (const float*)d_in[10];
    const float* b22        = (const float*)d_in[11];
    const float* Wo         = (const float*)d_in[12];
    const float* bo         = (const float*)d_in[13];
    const float* tau_adp_h1 = (const float*)d_in[14];
    const float* tau_adp_h2 = (const float*)d_in[15];
    const float* tau_m_h1   = (const float*)d_in[16];
    const float* tau_m_h2   = (const float*)d_in[17];
    const float* tau_m_o    = (const float*)d_in[18];

    float* U = (float*)d_ws;                            // [32001][256] f32
    float* C1 = U + ((size_t)BATCH * T + 1) * H;        // [257][512] f32
    float* C2 = C1 + N_C;                               // [257][512] f32
    unsigned short* Wi1p = (unsigned short*)(C2 + N_C); // [256][704] bf16

    int prep_total = 2 * N_C + N_WP;
    prep_k<<<(prep_total + 255) / 256, 256, 0, stream>>>(
        Wi1, W11, W12, W22, Wo, Wi1p, C1, C2);

    gemm_u_k<<<(BATCH * T) / 64, 256, 0, stream>>>(x, Wi1p, bi1, U);

    recurrent_k<<<BATCH, 256, 0, stream>>>(U, mem1_0, mem2_0, memo_0,
                                           b11, b12, b22, bo,
                                           tau_adp_h1, tau_adp_h2,
                                           tau_m_h1, tau_m_h2, tau_m_o,
                                           C1, C2, (float*)d_out);
}

// Round 2
// 886.370 us; speedup vs baseline: 1.5393x; 1.5393x over previous
//
#include <hip/hip_runtime.h>
#include <math.h>

#define BATCH 128
#define T 250
#define D_IN 700
#define H 256
#define D_OUT 20

typedef float v2f __attribute__((ext_vector_type(2)));
typedef __attribute__((ext_vector_type(8))) short bf16x8;
typedef __attribute__((ext_vector_type(4))) float f32x4;

static __device__ __forceinline__ unsigned short f2b(float f) {
    unsigned u = __float_as_uint(f);
    u += 0x7FFFu + ((u >> 16) & 1u);
    return (unsigned short)(u >> 16);
}

// Raw barrier: LDS ordering only (lgkmcnt). Deliberately NO vmcnt drain so
// global loads (u_nxt prefetch, gather pipeline) stay in flight across it.
static __device__ __forceinline__ void bar() {
    asm volatile("s_waitcnt lgkmcnt(0)" ::: "memory");
    __builtin_amdgcn_s_barrier();
    asm volatile("" ::: "memory");
}

// ---------------------------------------------------------------------------
// Workspace layout:
//   U     [32001][256] f32   (pad row: u-prefetch overrun at t=249)
//   C1    [257][512] f32     row k: q=2h -> W12T[k][h], q=2h+1 -> W11T[k][h]
//   C2    [257][512] f32     row k: q=2h -> W22T[k][h], q=2h+1 -> (h<20 ? Wo[h][k] : 0)
//   Wi1p  [256][704] bf16    cols 700..703 zero (MFMA K-pad)
//   row 256 of C1/C2 is all-zero (spike-list padding target)
// Column-split recurrent: thread tid owns columns {2*tid, 2*tid+1} of every
// row -> one v2f load per spike row; result lands on the owning neuron's
// thread, no cross-wave reduction.
// ---------------------------------------------------------------------------
#define N_C  (257 * 512)
#define N_WP (256 * 704)

__global__ void prep_k(const float* __restrict__ Wi1, const float* __restrict__ W11,
                       const float* __restrict__ W12, const float* __restrict__ W22,
                       const float* __restrict__ Wo,
                       unsigned short* __restrict__ Wi1p, float* __restrict__ C1,
                       float* __restrict__ C2) {
    int idx = blockIdx.x * 256 + threadIdx.x;
    if (idx < N_C) {
        int k = idx >> 9, q = idx & 511, h = q >> 1;
        float v = 0.f;
        if (k < H) v = (q & 1) ? W11[h * H + k] : W12[h * H + k];
        C1[idx] = v;
        return;
    }
    idx -= N_C;
    if (idx < N_C) {
        int k = idx >> 9, q = idx & 511, h = q >> 1;
        float v = 0.f;
        if (k < H) {
            if (q & 1) v = (h < D_OUT) ? Wo[h * H + k] : 0.f;
            else v = W22[h * H + k];
        }
        C2[idx] = v;
        return;
    }
    idx -= N_C;
    if (idx < N_WP) {
        int h = idx / 704, k = idx - h * 704;
        Wi1p[idx] = (k < D_IN) ? f2b(Wi1[h * D_IN + k]) : (unsigned short)0;
    }
}

// ---------------------------------------------------------------------------
// U = x @ Wi1^T + bi1 via MFMA 16x16x32 bf16 — UNCHANGED (proven).
// ---------------------------------------------------------------------------
__global__ __launch_bounds__(256) void gemm_u_k(const float* __restrict__ x,
                                                const unsigned short* __restrict__ Wi1p,
                                                const float* __restrict__ bi1,
                                                float* __restrict__ U) {
    const int lane = threadIdx.x & 63;
    const int wv = threadIdx.x >> 6;
    const int quad = lane >> 4;
    const int nl = lane & 15;
    const int mbase = blockIdx.x * 64 + wv * 16;
    const int m = mbase + nl;

    f32x4 acc[16];
#pragma unroll
    for (int i = 0; i < 16; ++i) acc[i] = (f32x4)(0.f);

    float bias[16];
#pragma unroll
    for (int nt = 0; nt < 16; ++nt) bias[nt] = bi1[nt * 16 + nl];

    const float* xrow = x + (size_t)m * D_IN;
    const unsigned short* brow = Wi1p + nl * 704 + quad * 8;

    for (int k0 = 0; k0 < 704; k0 += 32) {
        int ka = k0 + quad * 8;
        int ka2 = (ka + 4 <= 696) ? ka + 4 : 696;
        float4 q0 = *(const float4*)(xrow + ka);
        float4 q1 = *(const float4*)(xrow + ka2);
        bf16x8 af;
        af[0] = (short)f2b(q0.x); af[1] = (short)f2b(q0.y);
        af[2] = (short)f2b(q0.z); af[3] = (short)f2b(q0.w);
        af[4] = (short)f2b(q1.x); af[5] = (short)f2b(q1.y);
        af[6] = (short)f2b(q1.z); af[7] = (short)f2b(q1.w);

        const unsigned short* bp = brow + k0;
        bf16x8 bf[16];
#pragma unroll
        for (int nt = 0; nt < 16; ++nt)
            bf[nt] = *(const bf16x8*)(bp + nt * 16 * 704);
#pragma unroll
        for (int nt = 0; nt < 16; ++nt)
            acc[nt] = __builtin_amdgcn_mfma_f32_16x16x32_bf16(af, bf[nt], acc[nt], 0, 0, 0);
    }

#pragma unroll
    for (int nt = 0; nt < 16; ++nt) {
#pragma unroll
        for (int r = 0; r < 4; ++r) {
            U[(size_t)(mbase + quad * 4 + r) * H + nt * 16 + nl] = acc[nt][r] + bias[nt];
        }
    }
}

// ---------------------------------------------------------------------------
// Depth-32 column gather: 2 chunks x 16 rows in flight = 64 VGPR of buffers
// (dataflow-forced liveness; fits without spilling). Pads -> zero row 256.
// ---------------------------------------------------------------------------
static __device__ __forceinline__ void ldchunk(const unsigned* __restrict__ lst, int c,
                                               const float* __restrict__ Cb, unsigned toff,
                                               v2f* buf) {
    uint4 a = *(const uint4*)(lst + c);
    uint4 b = *(const uint4*)(lst + c + 4);
    uint4 d = *(const uint4*)(lst + c + 8);
    uint4 e = *(const uint4*)(lst + c + 12);
    unsigned I[16] = {a.x, a.y, a.z, a.w, b.x, b.y, b.z, b.w,
                      d.x, d.y, d.z, d.w, e.x, e.y, e.z, e.w};
#pragma unroll
    for (int j = 0; j < 16; ++j)
        buf[j] = *(const v2f*)(Cb + (I[j] << 9) + toff);
}

static __device__ __forceinline__ void acchunk(const v2f* buf, v2f& A0, v2f& A1) {
#pragma unroll
    for (int j = 0; j < 16; j += 2) { A0 += buf[j]; A1 += buf[j + 1]; }
}

static __device__ __forceinline__ v2f gather32(const unsigned* __restrict__ lst, int n,
                                               const float* __restrict__ Cb, unsigned toff) {
    v2f A0 = (v2f)(0.f), A1 = (v2f)(0.f);
    v2f b0[16], b1[16];
    int nr = (n + 15) & ~15;
    if (nr < 32) nr = 32;              // prologue always covers 32 entries (pads are zero rows)
    ldchunk(lst, 0,  Cb, toff, b0);
    ldchunk(lst, 16, Cb, toff, b1);
    int c = 32;
    for (; c + 32 <= nr; c += 32) {
        acchunk(b0, A0, A1); ldchunk(lst, c,      Cb, toff, b0);
        acchunk(b1, A0, A1); ldchunk(lst, c + 16, Cb, toff, b1);
    }
    if (nr - c == 16) {
        acchunk(b0, A0, A1); ldchunk(lst, c, Cb, toff, b0);
    }
    acchunk(b0, A0, A1);
    acchunk(b1, A0, A1);
    return A0 + A1;
}

// ---------------------------------------------------------------------------
// Recurrent: one BLOCK (4 waves, 256 threads) per batch element.
// Thread tid owns neuron tid of both layers. Spike lists in LDS; raw
// lgkm-only barriers (4/step); u-prefetch issued in gather-1's shadow.
// ---------------------------------------------------------------------------
__global__ __launch_bounds__(256, 1) void recurrent_k(
    const float* __restrict__ U,
    const float* __restrict__ mem1_0, const float* __restrict__ mem2_0,
    const float* __restrict__ memo_0,
    const float* __restrict__ b11v, const float* __restrict__ b12v,
    const float* __restrict__ b22v, const float* __restrict__ bov,
    const float* __restrict__ tau_adp_h1, const float* __restrict__ tau_adp_h2,
    const float* __restrict__ tau_m_h1, const float* __restrict__ tau_m_h2,
    const float* __restrict__ tau_m_o,
    const float* __restrict__ C1, const float* __restrict__ C2,
    float* __restrict__ out)
{
    const int tid = threadIdx.x;
    const int lane = tid & 63;
    const int w = tid >> 6;
    const int bi = blockIdx.x;
    const unsigned toff = 2u * (unsigned)tid;

    __shared__ __align__(16) unsigned list1[288];
    __shared__ __align__(16) unsigned list2[288];
    __shared__ __align__(16) unsigned cnt1[4];
    __shared__ __align__(16) unsigned cnt2[4];

    float mem1 = mem1_0[bi * H + tid];
    float mem2 = mem2_0[bi * H + tid];
    float b1 = 0.01f, b2s = 0.01f;
    float spk1 = 0.f, spk2 = 0.f;

    float al1 = expf(-1.f / tau_m_h1[tid]);
    float ro1 = expf(-1.f / tau_adp_h1[tid]);
    float al2 = expf(-1.f / tau_m_h2[tid]);
    float ro2 = expf(-1.f / tau_adp_h2[tid]);
    float oma1 = 1.f - al1, omr1 = 1.f - ro1;
    float oma2 = 1.f - al2, omr2 = 1.f - ro2;

    float b11r = b11v[tid];
    float bs2 = b12v[tid] + b22v[tid];

    float memo = 0.f, alpha_o = 0.f, bo_r = 0.f, accv = 0.f;
    if (tid < D_OUT) {
        memo = memo_0[bi * D_OUT + tid];
        alpha_o = expf(-1.f / tau_m_o[tid]);
        bo_r = bov[tid];
    }

    float g11c = 0.f, g22c = 0.f, aOc = 0.f;
    const float* Up = U + (size_t)bi * T * H + tid;
    float u_cur = *Up;
    const unsigned long long below = (1ull << lane) - 1ull;

    for (int t = 0; t < T; ++t) {
        if (t >= 1) {
            float o = bo_r + aOc;
            memo = memo * alpha_o + (1.f - alpha_o) * o;
            if (t >= 12 && w == 0) {
                float e = (lane < D_OUT) ? __expf(memo) : 0.f;
                float s = e;
#pragma unroll
                for (int d = 16; d >= 1; d >>= 1) s += __shfl_xor(s, d, 32);
                if (lane < D_OUT) accv += __fdividef(e, s);
            }
        }

        // ---- layer 1 neuron update (thread-local) ----
        float h1 = u_cur + b11r + g11c;
        b1 = ro1 * b1 + omr1 * spk1;
        float B1 = 0.01f + 1.8f * b1;
        mem1 = mem1 * al1 + oma1 * h1 - B1 * spk1;
        spk1 = (mem1 - B1 > 0.f) ? 1.f : 0.f;

        // ---- build shared spike list 1 (2 raw barriers) ----
        unsigned long long m1 = __ballot(spk1 != 0.f);
        if (lane == 0) cnt1[w] = (unsigned)__popcll(m1);
        bar();
        uint4 cc1 = *(const uint4*)cnt1;
        unsigned n1 = cc1.x + cc1.y + cc1.z + cc1.w;
        unsigned base1 = (w > 0 ? cc1.x : 0u) + (w > 1 ? cc1.y : 0u) + (w > 2 ? cc1.z : 0u);
        if (spk1 != 0.f) list1[base1 + (unsigned)__popcll(m1 & below)] = (unsigned)tid;
        if (tid < 32) list1[n1 + tid] = 256u;   // pads -> all-zero row
        bar();

        // u-prefetch issued here: overlaps gather1 (+ layer2 update + list2)
        float u_nxt = Up[H];
        Up += H;

        v2f G1 = gather32(list1, (int)n1, C1, toff);   // {g12[tid], g11[tid]}

        // ---- layer 2 neuron update ----
        float h2 = bs2 + g22c + G1.x;
        b2s = ro2 * b2s + omr2 * spk2;
        float B2 = 0.01f + 1.8f * b2s;
        mem2 = mem2 * al2 + oma2 * h2 - B2 * spk2;
        spk2 = (mem2 - B2 > 0.f) ? 1.f : 0.f;

        // ---- build shared spike list 2 ----
        unsigned long long m2 = __ballot(spk2 != 0.f);
        if (lane == 0) cnt2[w] = (unsigned)__popcll(m2);
        bar();
        uint4 cc2 = *(const uint4*)cnt2;
        unsigned n2 = cc2.x + cc2.y + cc2.z + cc2.w;
        unsigned base2 = (w > 0 ? cc2.x : 0u) + (w > 1 ? cc2.y : 0u) + (w > 2 ? cc2.z : 0u);
        if (spk2 != 0.f) list2[base2 + (unsigned)__popcll(m2 & below)] = (unsigned)tid;
        if (tid < 32) list2[n2 + tid] = 256u;
        bar();

        v2f G2 = gather32(list2, (int)n2, C2, toff);   // {g22[tid], aO[tid]}

        g11c = G1.y;
        g22c = G2.x;
        aOc = G2.y;
        u_cur = u_nxt;
    }

    // final flush (memo(T-1) + softmax)
    {
        float o = bo_r + aOc;
        memo = memo * alpha_o + (1.f - alpha_o) * o;
        if (w == 0) {
            float e = (lane < D_OUT) ? __expf(memo) : 0.f;
            float s = e;
#pragma unroll
            for (int d = 16; d >= 1; d >>= 1) s += __shfl_xor(s, d, 32);
            if (lane < D_OUT) accv += __fdividef(e, s);
        }
    }
    if (tid < D_OUT) out[bi * D_OUT + tid] = accv;
}

// ---------------------------------------------------------------------------
extern "C" void kernel_launch(void* const* d_in, const int* in_sizes, int n_in,
                              void* d_out, int out_size, void* d_ws, size_t ws_size,
                              hipStream_t stream) {
    const float* x          = (const float*)d_in[0];
    const float* mem1_0     = (const float*)d_in[1];
    const float* mem2_0     = (const float*)d_in[2];
    const float* memo_0     = (const float*)d_in[3];
    const float* Wi1        = (const float*)d_in[4];
    const float* bi1        = (const float*)d_in[5];
    const float* W11        = (const float*)d_in[6];
    const float* b11        = (const float*)d_in[7];
    const float* W12        = (const float*)d_in[8];
    const float* b12        = (const float*)d_in[9];
    const float* W22        = (const float*)d_in[10];
    const float* b22        = (const float*)d_in[11];
    const float* Wo         = (const float*)d_in[12];
    const float* bo         = (const float*)d_in[13];
    const float* tau_adp_h1 = (const float*)d_in[14];
    const float* tau_adp_h2 = (const float*)d_in[15];
    const float* tau_m_h1   = (const float*)d_in[16];
    const float* tau_m_h2   = (const float*)d_in[17];
    const float* tau_m_o    = (const float*)d_in[18];

    float* U = (float*)d_ws;                            // [32001][256] f32
    float* C1 = U + ((size_t)BATCH * T + 1) * H;        // [257][512] f32
    float* C2 = C1 + N_C;                               // [257][512] f32
    unsigned short* Wi1p = (unsigned short*)(C2 + N_C); // [256][704] bf16

    int prep_total = 2 * N_C + N_WP;
    prep_k<<<(prep_total + 255) / 256, 256, 0, stream>>>(
        Wi1, W11, W12, W22, Wo, Wi1p, C1, C2);

    gemm_u_k<<<(BATCH * T) / 64, 256, 0, stream>>>(x, Wi1p, bi1, U);

    recurrent_k<<<BATCH, 256, 0, stream>>>(U, mem1_0, mem2_0, memo_0,
                                           b11, b12, b22, bo,
                                           tau_adp_h1, tau_adp_h2,
                                           tau_m_h1, tau_m_h2, tau_m_o,
                                           C1, C2, (float*)d_out);
}